// Round 19
// baseline (102.086 us; speedup 1.0000x reference)
//
#include <hip/hip_runtime.h>
#include <stdint.h>
#include <stddef.h>

#define NB 4
#define NL 2048
#define MODEL 512
#define NH 8
#define HD 64

// Q pre-scale: (1/sqrt(64)) * log2(e) -> scores in log2 domain
#define QSCALE 0.18033688011112042f

typedef __attribute__((ext_vector_type(8))) short short8;
typedef __attribute__((ext_vector_type(8))) __bf16 bf16x8;
typedef __attribute__((ext_vector_type(4))) float f32x4;
typedef __attribute__((ext_vector_type(16))) float f32x16;
typedef __attribute__((ext_vector_type(2))) unsigned int u32x2;

// round-to-nearest-even fp32 -> bf16 (bit pattern)
static __device__ __forceinline__ unsigned short f2bf(float x) {
  union { float f; unsigned u; } v; v.f = x;
  unsigned r = v.u + 0x7FFFu + ((v.u >> 16) & 1u);
  return (unsigned short)(r >> 16);
}

// packed fp32x2 -> bf16x2 (single HW instruction)
static __device__ __forceinline__ unsigned cvtpk(float lo, float hi) {
  unsigned r;
  asm("v_cvt_pk_bf16_f32 %0, %1, %2" : "=v"(r) : "v"(lo), "v"(hi));
  return r;
}

// NOTE: raw inline-asm v_exp_f32 is PERMANENTLY BANNED — tried three times
// (r10: 1.4e-3, r16: 5.6e-3, r18 with s_nop hazard fix: 5.4e-3). The failure
// is deterministic numerical difference, not a hazard: __builtin_exp2f's
// lowering is NOT a bare v_exp_f32. Only __builtin_exp2f passes accuracy.

static __device__ __forceinline__ f32x4 mfma16(short8 a, short8 b, f32x4 c) {
  return __builtin_amdgcn_mfma_f32_16x16x32_bf16(
      __builtin_bit_cast(bf16x8, a), __builtin_bit_cast(bf16x8, b), c, 0, 0, 0);
}

static __device__ __forceinline__ f32x16 mfma32(short8 a, short8 b, f32x16 c) {
  return __builtin_amdgcn_mfma_f32_32x32x16_bf16(
      __builtin_bit_cast(bf16x8, a), __builtin_bit_cast(bf16x8, b), c, 0, 0, 0);
}

#define GLOAD_LDS(gp, lp)                                                      \
  __builtin_amdgcn_global_load_lds(                                            \
      (const __attribute__((address_space(1))) void*)(gp),                     \
      (__attribute__((address_space(3))) void*)(lp), 16, 0, 0)

// ---------------------------------------------------------------------------
// Merged Q/K/V projection: XCD-grouping swizzle + T14 async-STAGE prefetch,
// no waves-per-EU cap. (r17 version, verbatim — measured ~19 us, passing)
// ---------------------------------------------------------------------------
__global__ __launch_bounds__(256) void qkv512(const float* __restrict__ Aq,
                                              const float* __restrict__ Ak,
                                              const float* __restrict__ Av,
                                              const float* __restrict__ Wqp,
                                              const float* __restrict__ Wkp,
                                              const float* __restrict__ Wvp,
                                              unsigned short* __restrict__ Qo,
                                              unsigned short* __restrict__ Ko,
                                              unsigned short* __restrict__ Vto) {
  __shared__ unsigned short Alds[128][72];
  __shared__ unsigned short Wlds[128][72];

  // XCD-grouping: XCD (bid&7) gets logical blocks [(bid&7)*96, +96)
  const int lb = ((blockIdx.x & 7) * 96) + (blockIdx.x >> 3);
  const int which = lb >> 8;
  const int bid = lb & 255;
  const float* A = which == 0 ? Aq : which == 1 ? Ak : Av;
  const float* W = which == 0 ? Wqp : which == 1 ? Wkp : Wvp;

  const int tid = threadIdx.x;
  const int bn = bid & 3;
  const int bm = bid >> 2;
  const int mbase = bm * 128, nbase = bn * 128;
  const int wid = tid >> 6, lane = tid & 63;
  const int lo = lane & 15, grp = lane >> 4;
  const int wm = wid >> 1, wn = wid & 1;

  const float* Arow[8];
  const float* Wrow[8];
#pragma unroll
  for (int it = 0; it < 8; ++it) {
    int id = tid + it * 256, row = id >> 4, cg = id & 15;
    Arow[it] = A + (size_t)(mbase + row) * 512 + cg * 4;
    Wrow[it] = W + (size_t)(nbase + row) * 512 + cg * 4;
  }

  f32x4 acc[4][4] = {};
  float4 ra[8], rw[8];

  // prologue: kb = 0
#pragma unroll
  for (int it = 0; it < 8; ++it) { ra[it] = *(const float4*)Arow[it]; rw[it] = *(const float4*)Wrow[it]; }
#pragma unroll
  for (int it = 0; it < 8; ++it) {
    int id = tid + it * 256, row = id >> 4, cg = id & 15;
    uint2 wa; wa.x = cvtpk(ra[it].x, ra[it].y); wa.y = cvtpk(ra[it].z, ra[it].w);
    *(uint2*)&Alds[row][cg * 4] = wa;
    uint2 ww; ww.x = cvtpk(rw[it].x, rw[it].y); ww.y = cvtpk(rw[it].z, rw[it].w);
    *(uint2*)&Wlds[row][cg * 4] = ww;
  }
  __syncthreads();

#pragma unroll 1
  for (int kb = 0; kb < 8; ++kb) {
    if (kb < 7) {
#pragma unroll
      for (int it = 0; it < 8; ++it) {
        ra[it] = *(const float4*)(Arow[it] + (kb + 1) * 64);
        rw[it] = *(const float4*)(Wrow[it] + (kb + 1) * 64);
      }
    }

#pragma unroll
    for (int kk = 0; kk < 2; ++kk) {
      short8 aw[4], ba[4];
#pragma unroll
      for (int f = 0; f < 4; ++f)
        aw[f] = *(const short8*)&Wlds[wn * 64 + f * 16 + lo][kk * 32 + grp * 8];
#pragma unroll
      for (int f = 0; f < 4; ++f)
        ba[f] = *(const short8*)&Alds[wm * 64 + f * 16 + lo][kk * 32 + grp * 8];
#pragma unroll
      for (int mf = 0; mf < 4; ++mf)
#pragma unroll
        for (int nf = 0; nf < 4; ++nf)
          acc[mf][nf] = mfma16(aw[nf], ba[mf], acc[mf][nf]);
    }
    __syncthreads();

    if (kb < 7) {
#pragma unroll
      for (int it = 0; it < 8; ++it) {
        int id = tid + it * 256, row = id >> 4, cg = id & 15;
        uint2 wa; wa.x = cvtpk(ra[it].x, ra[it].y); wa.y = cvtpk(ra[it].z, ra[it].w);
        *(uint2*)&Alds[row][cg * 4] = wa;
        uint2 ww; ww.x = cvtpk(rw[it].x, rw[it].y); ww.y = cvtpk(rw[it].z, rw[it].w);
        *(uint2*)&Wlds[row][cg * 4] = ww;
      }
      __syncthreads();
    }
  }

  const float scale = (which == 0) ? QSCALE : 1.0f;
#pragma unroll
  for (int mf = 0; mf < 4; ++mf)
#pragma unroll
    for (int nf = 0; nf < 4; ++nf) {
      int m = mbase + wm * 64 + mf * 16 + lo;
      int n0 = nbase + wn * 64 + nf * 16 + grp * 4;
      f32x4 a = acc[mf][nf];
      if (which < 2) {
        unsigned short* C = which == 0 ? Qo : Ko;
        uint2 w;
        w.x = cvtpk(a[0] * scale, a[1] * scale);
        w.y = cvtpk(a[2] * scale, a[3] * scale);
        *(uint2*)(C + (size_t)m * 512 + n0) = w;
      } else {
        int b = m >> 11, s = m & 2047;
#pragma unroll
        for (int i = 0; i < 4; ++i)
          Vto[((size_t)b * 512 + n0 + i) * 2048 + s] = f2bf(a[i]);
      }
    }
}

// ---------------------------------------------------------------------------
// Output projection (bf16 A, fp32 out). 128x128 tile, grid 256, 512 thr,
// XCD-grouping swizzle + T14 async-STAGE prefetch (same pattern that gained
// +4us on qkv in r17; math identical, pure load scheduling).
// ---------------------------------------------------------------------------
__global__ __launch_bounds__(512) void gemmWo(const unsigned short* __restrict__ A,
                                              const float* __restrict__ W,
                                              float* __restrict__ C) {
  __shared__ unsigned short Alds[128][72];
  __shared__ unsigned short Wlds[128][72];

  const int lb = ((blockIdx.x & 7) << 5) + (blockIdx.x >> 3);
  const int tid = threadIdx.x;
  const int bn = lb & 3;
  const int bm = lb >> 2;
  const int mbase = bm * 128, nbase = bn * 128;
  const int wid = tid >> 6, lane = tid & 63;
  const int lo = lane & 15, grp = lane >> 4;
  const int wm = wid >> 2, wn = wid & 3;     // 2 x 4 waves, 64m x 32n each

  const unsigned short* Asrc[2];
  const float* Wsrc[4];
#pragma unroll
  for (int it = 0; it < 2; ++it) {
    int id = tid + it * 512, row = id >> 3, cg = id & 7;
    Asrc[it] = A + (size_t)(mbase + row) * 512 + cg * 8;
  }
#pragma unroll
  for (int it = 0; it < 4; ++it) {
    int id = tid + it * 512, row = id >> 4, cg = id & 15;
    Wsrc[it] = W + (size_t)(nbase + row) * 512 + cg * 4;
  }

  f32x4 acc[4][2] = {};
  uint4 rA[2]; float4 rW[4];

  // prologue kb = 0
#pragma unroll
  for (int it = 0; it < 2; ++it) rA[it] = *(const uint4*)Asrc[it];
#pragma unroll
  for (int it = 0; it < 4; ++it) rW[it] = *(const float4*)Wsrc[it];
#pragma unroll
  for (int it = 0; it < 2; ++it) {
    int id = tid + it * 512, row = id >> 3, cg = id & 7;
    *(uint4*)&Alds[row][cg * 8] = rA[it];
  }
#pragma unroll
  for (int it = 0; it < 4; ++it) {
    int id = tid + it * 512, row = id >> 4, cg = id & 15;
    uint2 w; w.x = cvtpk(rW[it].x, rW[it].y); w.y = cvtpk(rW[it].z, rW[it].w);
    *(uint2*)&Wlds[row][cg * 4] = w;
  }
  __syncthreads();

#pragma unroll 1
  for (int kb = 0; kb < 8; ++kb) {
    if (kb < 7) {
#pragma unroll
      for (int it = 0; it < 2; ++it) rA[it] = *(const uint4*)(Asrc[it] + (kb + 1) * 64);
#pragma unroll
      for (int it = 0; it < 4; ++it) rW[it] = *(const float4*)(Wsrc[it] + (kb + 1) * 64);
    }

#pragma unroll
    for (int kk = 0; kk < 2; ++kk) {
      short8 aw[2], ba[4];
#pragma unroll
      for (int f = 0; f < 2; ++f)
        aw[f] = *(const short8*)&Wlds[wn * 32 + f * 16 + lo][kk * 32 + grp * 8];
#pragma unroll
      for (int f = 0; f < 4; ++f)
        ba[f] = *(const short8*)&Alds[wm * 64 + f * 16 + lo][kk * 32 + grp * 8];
#pragma unroll
      for (int mf = 0; mf < 4; ++mf)
#pragma unroll
        for (int nf = 0; nf < 2; ++nf)
          acc[mf][nf] = mfma16(aw[nf], ba[mf], acc[mf][nf]);
    }
    __syncthreads();

    if (kb < 7) {
#pragma unroll
      for (int it = 0; it < 2; ++it) {
        int id = tid + it * 512, row = id >> 3, cg = id & 7;
        *(uint4*)&Alds[row][cg * 8] = rA[it];
      }
#pragma unroll
      for (int it = 0; it < 4; ++it) {
        int id = tid + it * 512, row = id >> 4, cg = id & 15;
        uint2 w; w.x = cvtpk(rW[it].x, rW[it].y); w.y = cvtpk(rW[it].z, rW[it].w);
        *(uint2*)&Wlds[row][cg * 4] = w;
      }
      __syncthreads();
    }
  }

#pragma unroll
  for (int mf = 0; mf < 4; ++mf)
#pragma unroll
    for (int nf = 0; nf < 2; ++nf) {
      int m = mbase + wm * 64 + mf * 16 + lo;
      int n0 = nbase + wn * 32 + nf * 16 + grp * 4;
      f32x4 a = acc[mf][nf];
      float4 o;
      o.x = a[0]; o.y = a[1]; o.z = a[2]; o.w = a[3];
      *(float4*)(C + (size_t)m * 512 + n0) = o;
    }
}

// ---------------------------------------------------------------------------
// Flash attention: r13 version VERBATIM (__builtin_exp2f — the only
// accuracy-proven exp2 path). Half-tile pipeline: QK-h1 -> QK-h2 ||
// softmax-h1 -> PV-h1 || softmax-h2 -> PV-h2. Unnormalized softmax, l via
// ones-MFMA, in-register P (cvt_pk + permlane32_swap), K+V LDS DMA
// (pre-swizzled source, XOR b128 reads), dbuf. Grid 512 x 4 waves.
// ---------------------------------------------------------------------------
__global__ __launch_bounds__(256, 2) void attn64(const unsigned short* __restrict__ Qg,
                                                 const unsigned short* __restrict__ Kg,
                                                 const unsigned short* __restrict__ Vt,
                                                 unsigned short* __restrict__ Og) {
  __shared__ __align__(16) char LDS[65536];
  char* Kbase = LDS;            // [sh][buf][8192]
  char* Vbase = LDS + 32768;    // [sh][buf][8192]
  float* cb = (float*)LDS;      // combine buffer (aliases K/V, used after loop)

  const int tid = threadIdx.x;
  const int wid = tid >> 6, lane = tid & 63;
  const int ln31 = lane & 31, hl = lane >> 5;
  const int qh = wid & 1, sh = wid >> 1;

  // XCD chunk swizzle: each XCD gets 64 consecutive lb = 4 bh groups
  const int lb = ((blockIdx.x & 7) << 6) | (blockIdx.x >> 3);
  const int bh = lb >> 4, qb = lb & 15;
  const int b = bh >> 3, h = bh & 7;

  const unsigned short* Kbh = Kg + (size_t)b * 2048 * 512 + h * 64;
  const unsigned short* Vbh = Vt + ((size_t)b * 512 + h * 64) * 2048;

  const int q0 = qb * 128 + qh * 64 + ln31;   // chain A q; chain B = q0+32

  short8 qfA[4], qfB[4];
#pragma unroll
  for (int ks = 0; ks < 4; ++ks) {
    qfA[ks] = *(const short8*)(Qg + ((size_t)b * 2048 + q0) * 512 + h * 64 + ks * 16 + hl * 8);
    qfB[ks] = *(const short8*)(Qg + ((size_t)b * 2048 + q0 + 32) * 512 + h * 64 + ks * 16 + hl * 8);
  }

  const int srow = lane >> 3;
  const int schunk = (lane & 7) ^ srow;
  const unsigned short* kgp = Kbh + (size_t)(sh * 16 * 64 + qh * 32 + srow) * 512 + schunk * 8;
  const unsigned short* vgp = Vbh + (size_t)(qh * 32 + srow) * 2048 + sh * 16 * 64 + schunk * 8;
  char* kd = Kbase + sh * 16384;
  char* vd = Vbase + sh * 16384;
  const int wofs = qh * 4096;

  const int rb0 = ln31 * 128, rb1 = rb0 + 4096;
  const int sw = (ln31 & 7) << 4;
  const int hl16 = hl * 16;

  const short8 ones = {0x3F80, 0x3F80, 0x3F80, 0x3F80, 0x3F80, 0x3F80, 0x3F80, 0x3F80};
  f32x16 oA0 = {}, oA1 = {}, oB0 = {}, oB1 = {}, lA = {}, lB = {};

  // prologue: stage this half's tile 0
#pragma unroll
  for (int g = 0; g < 4; ++g) {
    GLOAD_LDS(kgp + (size_t)g * 8 * 512, kd + wofs + g * 1024);
    GLOAD_LDS(vgp + (size_t)g * 8 * 2048, vd + wofs + g * 1024);
  }
  __syncthreads();

  int cur = 0;
#pragma unroll 1
  for (int t = 0; t < 16; ++t) {
    if (t < 15) {
      const unsigned short* kp = kgp + (size_t)(t + 1) * 64 * 512;
      const unsigned short* vp = vgp + (t + 1) * 64;
      char* kdn = kd + (cur ^ 1) * 8192 + wofs;
      char* vdn = vd + (cur ^ 1) * 8192 + wofs;
#pragma unroll
      for (int g = 0; g < 4; ++g) {
        GLOAD_LDS(kp + (size_t)g * 8 * 512, kdn + g * 1024);
        GLOAD_LDS(vp + (size_t)g * 8 * 2048, vdn + g * 1024);
      }
    }

    const char* kr = kd + cur * 8192;
    const char* vr = vd + cur * 8192;

    // ================= QK half1: s-rows 0..31 =================
    f32x16 sA0 = {}, sB0 = {};
#pragma unroll
    for (int ks = 0; ks < 4; ++ks) {
      short8 k0 = *(const short8*)(kr + rb0 + ((ks * 32 + hl16) ^ sw));
      sA0 = mfma32(k0, qfA[ks], sA0);
      sB0 = mfma32(k0, qfB[ks], sB0);
    }
    // ================= QK half2: s-rows 32..63 =================
    f32x16 sA1 = {}, sB1 = {};
#pragma unroll
    for (int ks = 0; ks < 4; ++ks) {
      short8 k1 = *(const short8*)(kr + rb1 + ((ks * 32 + hl16) ^ sw));
      sA1 = mfma32(k1, qfA[ks], sA1);
      sB1 = mfma32(k1, qfB[ks], sB1);
    }

    // ===== softmax half1 (VALU; overlaps QK half2's MFMA issue) =====
    unsigned cA0[8], cB0[8];
#pragma unroll
    for (int i = 0; i < 8; ++i)
      cA0[i] = cvtpk(__builtin_exp2f(sA0[2 * i]), __builtin_exp2f(sA0[2 * i + 1]));
#pragma unroll
    for (int i = 0; i < 8; ++i)
      cB0[i] = cvtpk(__builtin_exp2f(sB0[2 * i]), __builtin_exp2f(sB0[2 * i + 1]));
    {
      u32x2 r;
      r = __builtin_amdgcn_permlane32_swap(cA0[0], cA0[2], false, false); cA0[0] = r[0]; cA0[2] = r[1];
      r = __builtin_amdgcn_permlane32_swap(cA0[1], cA0[3], false, false); cA0[1] = r[0]; cA0[3] = r[1];
      r = __builtin_amdgcn_permlane32_swap(cA0[4], cA0[6], false, false); cA0[4] = r[0]; cA0[6] = r[1];
      r = __builtin_amdgcn_permlane32_swap(cA0[5], cA0[7], false, false); cA0[5] = r[0]; cA0[7] = r[1];
      r = __builtin_amdgcn_permlane32_swap(cB0[0], cB0[2], false, false); cB0[0] = r[0]; cB0[2] = r[1];
      r = __builtin_amdgcn_permlane32_swap(cB0[1], cB0[3], false, false); cB0[1] = r[0]; cB0[3] = r[1];
      r = __builtin_amdgcn_permlane32_swap(cB0[4], cB0[6], false, false); cB0[4] = r[0]; cB0[6] = r[1];
      r = __builtin_amdgcn_permlane32_swap(cB0[5], cB0[7], false, false); cB0[5] = r[0]; cB0[7] = r[1];
    }
    short8 pfA0, pfA1, pfB0, pfB1;
    {
      union { unsigned u[4]; short8 s; } t2;
      t2.u[0] = cA0[0]; t2.u[1] = cA0[1]; t2.u[2] = cA0[2]; t2.u[3] = cA0[3]; pfA0 = t2.s;
      t2.u[0] = cA0[4]; t2.u[1] = cA0[5]; t2.u[2] = cA0[6]; t2.u[3] = cA0[7]; pfA1 = t2.s;
      t2.u[0] = cB0[0]; t2.u[1] = cB0[1]; t2.u[2] = cB0[2]; t2.u[3] = cB0[3]; pfB0 = t2.s;
      t2.u[0] = cB0[4]; t2.u[1] = cB0[5]; t2.u[2] = cB0[6]; t2.u[3] = cB0[7]; pfB1 = t2.s;
    }

    // ================= PV half1 (ks 0,1) =================
#pragma unroll
    for (int ks = 0; ks < 2; ++ks) {
      short8 pf = ks ? pfA1 : pfA0;
      short8 pg = ks ? pfB1 : pfB0;
      short8 v0 = *(const short8*)(vr + rb0 + ((ks * 32 + hl16) ^ sw));
      short8 v1 = *(const short8*)(vr + rb1 + ((ks * 32 + hl16) ^ sw));
      oA0 = mfma32(v0, pf, oA0);
      oA1 = mfma32(v1, pf, oA1);
      oB0 = mfma32(v0, pg, oB0);
      oB1 = mfma32(v1, pg, oB1);
      lA = mfma32(ones, pf, lA);
      lB = mfma32(ones, pg, lB);
    }

    // ===== softmax half2 (VALU; overlaps PV half1's MFMA issue) =====
    unsigned cA1[8], cB1[8];
#pragma unroll
    for (int i = 0; i < 8; ++i)
      cA1[i] = cvtpk(__builtin_exp2f(sA1[2 * i]), __builtin_exp2f(sA1[2 * i + 1]));
#pragma unroll
    for (int i = 0; i < 8; ++i)
      cB1[i] = cvtpk(__builtin_exp2f(sB1[2 * i]), __builtin_exp2f(sB1[2 * i + 1]));
    {
      u32x2 r;
      r = __builtin_amdgcn_permlane32_swap(cA1[0], cA1[2], false, false); cA1[0] = r[0]; cA1[2] = r[1];
      r = __builtin_amdgcn_permlane32_swap(cA1[1], cA1[3], false, false); cA1[1] = r[0]; cA1[3] = r[1];
      r = __builtin_amdgcn_permlane32_swap(cA1[4], cA1[6], false, false); cA1[4] = r[0]; cA1[6] = r[1];
      r = __builtin_amdgcn_permlane32_swap(cA1[5], cA1[7], false, false); cA1[5] = r[0]; cA1[7] = r[1];
      r = __builtin_amdgcn_permlane32_swap(cB1[0], cB1[2], false, false); cB1[0] = r[0]; cB1[2] = r[1];
      r = __builtin_amdgcn_permlane32_swap(cB1[1], cB1[3], false, false); cB1[1] = r[0]; cB1[3] = r[1];
      r = __builtin_amdgcn_permlane32_swap(cB1[4], cB1[6], false, false); cB1[4] = r[0]; cB1[6] = r[1];
      r = __builtin_amdgcn_permlane32_swap(cB1[5], cB1[7], false, false); cB1[5] = r[0]; cB1[7] = r[1];
    }
    short8 pfA2, pfA3, pfB2, pfB3;
    {
      union { unsigned u[4]; short8 s; } t2;
      t2.u[0] = cA1[0]; t2.u[1] = cA1[1]; t2.u[2] = cA1[2]; t2.u[3] = cA1[3]; pfA2 = t2.s;
      t2.u[0] = cA1[4]; t2.u[1] = cA1[5]; t2.u[2] = cA1[6]; t2.u[3] = cA1[7]; pfA3 = t2.s;
      t2.u[0] = cB1[0]; t2.u[1] = cB1[1]; t2.u[2] = cB1[2]; t2.u[3] = cB1[3]; pfB2 = t2.s;
      t2.u[0] = cB1[4]; t2.u[1] = cB1[5]; t2.u[2] = cB1[6]; t2.u[3] = cB1[7]; pfB3 = t2.s;
    }

    // ================= PV half2 (ks 2,3) =================
#pragma unroll
    for (int ks = 2; ks < 4; ++ks) {
      short8 pf = (ks == 2) ? pfA2 : pfA3;
      short8 pg = (ks == 2) ? pfB2 : pfB3;
      short8 v0 = *(const short8*)(vr + rb0 + ((ks * 32 + hl16) ^ sw));
      short8 v1 = *(const short8*)(vr + rb1 + ((ks * 32 + hl16) ^ sw));
      oA0 = mfma32(v0, pf, oA0);
      oA1 = mfma32(v1, pf, oA1);
      oB0 = mfma32(v0, pg, oB0);
      oB1 = mfma32(v1, pg, oB1);
      lA = mfma32(ones, pf, lA);
      lB = mfma32(ones, pg, lB);
    }

    __syncthreads();
    cur ^= 1;
  }

  // ---- combine s-halves (trivial: o and l just add) ----
  float* myc = cb + (size_t)(qh * 64 + lane) * 68;
  if (sh == 1) {
    float4* c4 = (float4*)myc;
#pragma unroll
    for (int i = 0; i < 4; ++i) {
      c4[i]      = make_float4(oA0[4*i], oA0[4*i+1], oA0[4*i+2], oA0[4*i+3]);
      c4[4 + i]  = make_float4(oA1[4*i], oA1[4*i+1], oA1[4*i+2], oA1[4*i+3]);
      c4[8 + i]  = make_float4(oB0[4*i], oB0[4*i+1], oB0[4*i+2], oB0[4*i+3]);
      c4[12 + i] = make_float4(oB1[4*i], oB1[4*i+1], oB1[4*i+2], oB1[4*i+3]);
    }
    myc[64] = lA[0]; myc[65] = lB[0];
  }
  __syncthreads();
  if (sh == 0) {
#pragma unroll
    for (int i = 0; i < 16; ++i) {
      oA0[i] += myc[i];      oA1[i] += myc[16 + i];
      oB0[i] += myc[32 + i]; oB1[i] += myc[48 + i];
    }
    float invA = 1.f / (lA[0] + myc[64]);
    float invB = 1.f / (lB[0] + myc[65]);

#pragma unroll
    for (int dblk = 0; dblk < 2; ++dblk) {
      const f32x16& a = dblk ? oA1 : oA0;
      const f32x16& bb = dblk ? oB1 : oB0;
#pragma unroll
      for (int rg = 0; rg < 4; ++rg) {
        int d0 = dblk * 32 + rg * 8 + hl * 4;
        uint2 w;
        w.x = cvtpk(a[rg * 4 + 0] * invA, a[rg * 4 + 1] * invA);
        w.y = cvtpk(a[rg * 4 + 2] * invA, a[rg * 4 + 3] * invA);
        *(uint2*)(Og + ((size_t)b * 2048 + q0) * 512 + h * 64 + d0) = w;
        w.x = cvtpk(bb[rg * 4 + 0] * invB, bb[rg * 4 + 1] * invB);
        w.y = cvtpk(bb[rg * 4 + 2] * invB, bb[rg * 4 + 3] * invB);
        *(uint2*)(Og + ((size_t)b * 2048 + q0 + 32) * 512 + h * 64 + d0) = w;
      }
    }
  }
}

// ---------------------------------------------------------------------------
extern "C" void kernel_launch(void* const* d_in, const int* in_sizes, int n_in,
                              void* d_out, int out_size, void* d_ws, size_t ws_size,
                              hipStream_t stream) {
  (void)in_sizes; (void)n_in; (void)out_size; (void)ws_size;
  const float* query = (const float*)d_in[0];
  const float* key   = (const float*)d_in[1];
  const float* value = (const float*)d_in[2];
  const float* Wq    = (const float*)d_in[3];
  const float* Wk    = (const float*)d_in[4];
  const float* Wv    = (const float*)d_in[5];
  const float* Wo    = (const float*)d_in[6];

  const size_t TOK = (size_t)NB * NL * MODEL;
  unsigned short* Qw = (unsigned short*)d_ws;
  unsigned short* Kw = Qw + TOK;
  unsigned short* Vw = Kw + TOK;   // transposed [b][h*64+d][s]
  unsigned short* Aw = Vw + TOK;   // attended [b][l][512]

  qkv512<<<768, 256, 0, stream>>>(query, key, value, Wq, Wk, Wv, Qw, Kw, Vw);
  attn64<<<512, 256, 0, stream>>>(Qw, Kw, Vw, Aw);
  gemmWo<<<256, 512, 0, stream>>>(Aw, Wo, (float*)d_out);
}

// Round 20
// 100.302 us; speedup vs baseline: 1.0178x; 1.0178x over previous
//
#include <hip/hip_runtime.h>
#include <stdint.h>
#include <stddef.h>

#define NB 4
#define NL 2048
#define MODEL 512
#define NH 8
#define HD 64

// Q pre-scale: (1/sqrt(64)) * log2(e) -> scores in log2 domain
#define QSCALE 0.18033688011112042f

typedef __attribute__((ext_vector_type(8))) short short8;
typedef __attribute__((ext_vector_type(8))) __bf16 bf16x8;
typedef __attribute__((ext_vector_type(4))) float f32x4;
typedef __attribute__((ext_vector_type(16))) float f32x16;
typedef __attribute__((ext_vector_type(2))) unsigned int u32x2;

// round-to-nearest-even fp32 -> bf16 (bit pattern)
static __device__ __forceinline__ unsigned short f2bf(float x) {
  union { float f; unsigned u; } v; v.f = x;
  unsigned r = v.u + 0x7FFFu + ((v.u >> 16) & 1u);
  return (unsigned short)(r >> 16);
}

// packed fp32x2 -> bf16x2 (single HW instruction)
static __device__ __forceinline__ unsigned cvtpk(float lo, float hi) {
  unsigned r;
  asm("v_cvt_pk_bf16_f32 %0, %1, %2" : "=v"(r) : "v"(lo), "v"(hi));
  return r;
}

// NOTE: raw inline-asm v_exp_f32 is PERMANENTLY BANNED — tried three times
// (r10: 1.4e-3, r16: 5.6e-3, r18 with s_nop hazard fix: 5.4e-3). The failure
// is a deterministic numerical difference: __builtin_exp2f's lowering is NOT
// a bare v_exp_f32. Only __builtin_exp2f passes accuracy here.

static __device__ __forceinline__ f32x4 mfma16(short8 a, short8 b, f32x4 c) {
  return __builtin_amdgcn_mfma_f32_16x16x32_bf16(
      __builtin_bit_cast(bf16x8, a), __builtin_bit_cast(bf16x8, b), c, 0, 0, 0);
}

static __device__ __forceinline__ f32x16 mfma32(short8 a, short8 b, f32x16 c) {
  return __builtin_amdgcn_mfma_f32_32x32x16_bf16(
      __builtin_bit_cast(bf16x8, a), __builtin_bit_cast(bf16x8, b), c, 0, 0, 0);
}

#define GLOAD_LDS(gp, lp)                                                      \
  __builtin_amdgcn_global_load_lds(                                            \
      (const __attribute__((address_space(1))) void*)(gp),                     \
      (__attribute__((address_space(3))) void*)(lp), 16, 0, 0)

// ---------------------------------------------------------------------------
// Merged Q/K/V projection: XCD-grouping swizzle + T14 async-STAGE prefetch,
// no waves-per-EU cap. (r17 version, verbatim — best measured, ~19 us)
// ---------------------------------------------------------------------------
__global__ __launch_bounds__(256) void qkv512(const float* __restrict__ Aq,
                                              const float* __restrict__ Ak,
                                              const float* __restrict__ Av,
                                              const float* __restrict__ Wqp,
                                              const float* __restrict__ Wkp,
                                              const float* __restrict__ Wvp,
                                              unsigned short* __restrict__ Qo,
                                              unsigned short* __restrict__ Ko,
                                              unsigned short* __restrict__ Vto) {
  __shared__ unsigned short Alds[128][72];
  __shared__ unsigned short Wlds[128][72];

  // XCD-grouping: XCD (bid&7) gets logical blocks [(bid&7)*96, +96)
  const int lb = ((blockIdx.x & 7) * 96) + (blockIdx.x >> 3);
  const int which = lb >> 8;
  const int bid = lb & 255;
  const float* A = which == 0 ? Aq : which == 1 ? Ak : Av;
  const float* W = which == 0 ? Wqp : which == 1 ? Wkp : Wvp;

  const int tid = threadIdx.x;
  const int bn = bid & 3;
  const int bm = bid >> 2;
  const int mbase = bm * 128, nbase = bn * 128;
  const int wid = tid >> 6, lane = tid & 63;
  const int lo = lane & 15, grp = lane >> 4;
  const int wm = wid >> 1, wn = wid & 1;

  const float* Arow[8];
  const float* Wrow[8];
#pragma unroll
  for (int it = 0; it < 8; ++it) {
    int id = tid + it * 256, row = id >> 4, cg = id & 15;
    Arow[it] = A + (size_t)(mbase + row) * 512 + cg * 4;
    Wrow[it] = W + (size_t)(nbase + row) * 512 + cg * 4;
  }

  f32x4 acc[4][4] = {};
  float4 ra[8], rw[8];

  // prologue: kb = 0
#pragma unroll
  for (int it = 0; it < 8; ++it) { ra[it] = *(const float4*)Arow[it]; rw[it] = *(const float4*)Wrow[it]; }
#pragma unroll
  for (int it = 0; it < 8; ++it) {
    int id = tid + it * 256, row = id >> 4, cg = id & 15;
    uint2 wa; wa.x = cvtpk(ra[it].x, ra[it].y); wa.y = cvtpk(ra[it].z, ra[it].w);
    *(uint2*)&Alds[row][cg * 4] = wa;
    uint2 ww; ww.x = cvtpk(rw[it].x, rw[it].y); ww.y = cvtpk(rw[it].z, rw[it].w);
    *(uint2*)&Wlds[row][cg * 4] = ww;
  }
  __syncthreads();

#pragma unroll 1
  for (int kb = 0; kb < 8; ++kb) {
    if (kb < 7) {
#pragma unroll
      for (int it = 0; it < 8; ++it) {
        ra[it] = *(const float4*)(Arow[it] + (kb + 1) * 64);
        rw[it] = *(const float4*)(Wrow[it] + (kb + 1) * 64);
      }
    }

#pragma unroll
    for (int kk = 0; kk < 2; ++kk) {
      short8 aw[4], ba[4];
#pragma unroll
      for (int f = 0; f < 4; ++f)
        aw[f] = *(const short8*)&Wlds[wn * 64 + f * 16 + lo][kk * 32 + grp * 8];
#pragma unroll
      for (int f = 0; f < 4; ++f)
        ba[f] = *(const short8*)&Alds[wm * 64 + f * 16 + lo][kk * 32 + grp * 8];
#pragma unroll
      for (int mf = 0; mf < 4; ++mf)
#pragma unroll
        for (int nf = 0; nf < 4; ++nf)
          acc[mf][nf] = mfma16(aw[nf], ba[mf], acc[mf][nf]);
    }
    __syncthreads();

    if (kb < 7) {
#pragma unroll
      for (int it = 0; it < 8; ++it) {
        int id = tid + it * 256, row = id >> 4, cg = id & 15;
        uint2 wa; wa.x = cvtpk(ra[it].x, ra[it].y); wa.y = cvtpk(ra[it].z, ra[it].w);
        *(uint2*)&Alds[row][cg * 4] = wa;
        uint2 ww; ww.x = cvtpk(rw[it].x, rw[it].y); ww.y = cvtpk(rw[it].z, rw[it].w);
        *(uint2*)&Wlds[row][cg * 4] = ww;
      }
      __syncthreads();
    }
  }

  const float scale = (which == 0) ? QSCALE : 1.0f;
#pragma unroll
  for (int mf = 0; mf < 4; ++mf)
#pragma unroll
    for (int nf = 0; nf < 4; ++nf) {
      int m = mbase + wm * 64 + mf * 16 + lo;
      int n0 = nbase + wn * 64 + nf * 16 + grp * 4;
      f32x4 a = acc[mf][nf];
      if (which < 2) {
        unsigned short* C = which == 0 ? Qo : Ko;
        uint2 w;
        w.x = cvtpk(a[0] * scale, a[1] * scale);
        w.y = cvtpk(a[2] * scale, a[3] * scale);
        *(uint2*)(C + (size_t)m * 512 + n0) = w;
      } else {
        int b = m >> 11, s = m & 2047;
#pragma unroll
        for (int i = 0; i < 4; ++i)
          Vto[((size_t)b * 512 + n0 + i) * 2048 + s] = f2bf(a[i]);
      }
    }
}

// ---------------------------------------------------------------------------
// Output projection (bf16 A, fp32 out). 128x128 tile, grid 256, 512 thr,
// XCD-grouping swizzle, NO prefetch (r15 version — r19 showed prefetch is
// neutral-to-negative here; staging is already cheap).
// ---------------------------------------------------------------------------
__global__ __launch_bounds__(512) void gemmWo(const unsigned short* __restrict__ A,
                                              const float* __restrict__ W,
                                              float* __restrict__ C) {
  __shared__ unsigned short Alds[128][72];
  __shared__ unsigned short Wlds[128][72];

  const int lb = ((blockIdx.x & 7) << 5) + (blockIdx.x >> 3);
  const int tid = threadIdx.x;
  const int bn = lb & 3;
  const int bm = lb >> 2;
  const int mbase = bm * 128, nbase = bn * 128;
  const int wid = tid >> 6, lane = tid & 63;
  const int lo = lane & 15, grp = lane >> 4;
  const int wm = wid >> 2, wn = wid & 3;     // 2 x 4 waves, 64m x 32n each

  f32x4 acc[4][2] = {};

#pragma unroll 1
  for (int kb = 0; kb < 8; ++kb) {
#pragma unroll
    for (int it = 0; it < 2; ++it) {
      int id = tid + it * 512;
      int row = id >> 3, cg = id & 7;
      uint4 v = *(const uint4*)(A + (size_t)(mbase + row) * 512 + kb * 64 + cg * 8);
      *(uint4*)&Alds[row][cg * 8] = v;
    }
#pragma unroll
    for (int it = 0; it < 4; ++it) {
      int id = tid + it * 512;
      int row = id >> 4, cg = id & 15;
      float4 v = *(const float4*)(W + (size_t)(nbase + row) * 512 + kb * 64 + cg * 4);
      uint2 w; w.x = cvtpk(v.x, v.y); w.y = cvtpk(v.z, v.w);
      *(uint2*)&Wlds[row][cg * 4] = w;
    }
    __syncthreads();

#pragma unroll
    for (int kk = 0; kk < 2; ++kk) {
      short8 aw[2], ba[4];
#pragma unroll
      for (int f = 0; f < 2; ++f)
        aw[f] = *(const short8*)&Wlds[wn * 32 + f * 16 + lo][kk * 32 + grp * 8];
#pragma unroll
      for (int f = 0; f < 4; ++f)
        ba[f] = *(const short8*)&Alds[wm * 64 + f * 16 + lo][kk * 32 + grp * 8];
#pragma unroll
      for (int mf = 0; mf < 4; ++mf)
#pragma unroll
        for (int nf = 0; nf < 2; ++nf)
          acc[mf][nf] = mfma16(aw[nf], ba[mf], acc[mf][nf]);
    }
    __syncthreads();
  }

#pragma unroll
  for (int mf = 0; mf < 4; ++mf)
#pragma unroll
    for (int nf = 0; nf < 2; ++nf) {
      int m = mbase + wm * 64 + mf * 16 + lo;
      int n0 = nbase + wn * 32 + nf * 16 + grp * 4;
      f32x4 a = acc[mf][nf];
      float4 o;
      o.x = a[0]; o.y = a[1]; o.z = a[2]; o.w = a[3];
      *(float4*)(C + (size_t)m * 512 + n0) = o;
    }
}

// ---------------------------------------------------------------------------
// Flash attention: r13 version VERBATIM (__builtin_exp2f — the only
// accuracy-proven exp2 path; measured 62.4-63.2 us). Half-tile pipeline:
// QK-h1 -> QK-h2 || softmax-h1 -> PV-h1 || softmax-h2 -> PV-h2.
// Unnormalized softmax, l via ones-MFMA, in-register P (cvt_pk +
// permlane32_swap), K+V LDS DMA (pre-swizzled source, XOR b128 reads),
// dbuf. Grid 512 x 4 waves, XCD chunk swizzle.
// ---------------------------------------------------------------------------
__global__ __launch_bounds__(256, 2) void attn64(const unsigned short* __restrict__ Qg,
                                                 const unsigned short* __restrict__ Kg,
                                                 const unsigned short* __restrict__ Vt,
                                                 unsigned short* __restrict__ Og) {
  __shared__ __align__(16) char LDS[65536];
  char* Kbase = LDS;            // [sh][buf][8192]
  char* Vbase = LDS + 32768;    // [sh][buf][8192]
  float* cb = (float*)LDS;      // combine buffer (aliases K/V, used after loop)

  const int tid = threadIdx.x;
  const int wid = tid >> 6, lane = tid & 63;
  const int ln31 = lane & 31, hl = lane >> 5;
  const int qh = wid & 1, sh = wid >> 1;

  // XCD chunk swizzle: each XCD gets 64 consecutive lb = 4 bh groups
  const int lb = ((blockIdx.x & 7) << 6) | (blockIdx.x >> 3);
  const int bh = lb >> 4, qb = lb & 15;
  const int b = bh >> 3, h = bh & 7;

  const unsigned short* Kbh = Kg + (size_t)b * 2048 * 512 + h * 64;
  const unsigned short* Vbh = Vt + ((size_t)b * 512 + h * 64) * 2048;

  const int q0 = qb * 128 + qh * 64 + ln31;   // chain A q; chain B = q0+32

  short8 qfA[4], qfB[4];
#pragma unroll
  for (int ks = 0; ks < 4; ++ks) {
    qfA[ks] = *(const short8*)(Qg + ((size_t)b * 2048 + q0) * 512 + h * 64 + ks * 16 + hl * 8);
    qfB[ks] = *(const short8*)(Qg + ((size_t)b * 2048 + q0 + 32) * 512 + h * 64 + ks * 16 + hl * 8);
  }

  const int srow = lane >> 3;
  const int schunk = (lane & 7) ^ srow;
  const unsigned short* kgp = Kbh + (size_t)(sh * 16 * 64 + qh * 32 + srow) * 512 + schunk * 8;
  const unsigned short* vgp = Vbh + (size_t)(qh * 32 + srow) * 2048 + sh * 16 * 64 + schunk * 8;
  char* kd = Kbase + sh * 16384;
  char* vd = Vbase + sh * 16384;
  const int wofs = qh * 4096;

  const int rb0 = ln31 * 128, rb1 = rb0 + 4096;
  const int sw = (ln31 & 7) << 4;
  const int hl16 = hl * 16;

  const short8 ones = {0x3F80, 0x3F80, 0x3F80, 0x3F80, 0x3F80, 0x3F80, 0x3F80, 0x3F80};
  f32x16 oA0 = {}, oA1 = {}, oB0 = {}, oB1 = {}, lA = {}, lB = {};

  // prologue: stage this half's tile 0
#pragma unroll
  for (int g = 0; g < 4; ++g) {
    GLOAD_LDS(kgp + (size_t)g * 8 * 512, kd + wofs + g * 1024);
    GLOAD_LDS(vgp + (size_t)g * 8 * 2048, vd + wofs + g * 1024);
  }
  __syncthreads();

  int cur = 0;
#pragma unroll 1
  for (int t = 0; t < 16; ++t) {
    if (t < 15) {
      const unsigned short* kp = kgp + (size_t)(t + 1) * 64 * 512;
      const unsigned short* vp = vgp + (t + 1) * 64;
      char* kdn = kd + (cur ^ 1) * 8192 + wofs;
      char* vdn = vd + (cur ^ 1) * 8192 + wofs;
#pragma unroll
      for (int g = 0; g < 4; ++g) {
        GLOAD_LDS(kp + (size_t)g * 8 * 512, kdn + g * 1024);
        GLOAD_LDS(vp + (size_t)g * 8 * 2048, vdn + g * 1024);
      }
    }

    const char* kr = kd + cur * 8192;
    const char* vr = vd + cur * 8192;

    // ================= QK half1: s-rows 0..31 =================
    f32x16 sA0 = {}, sB0 = {};
#pragma unroll
    for (int ks = 0; ks < 4; ++ks) {
      short8 k0 = *(const short8*)(kr + rb0 + ((ks * 32 + hl16) ^ sw));
      sA0 = mfma32(k0, qfA[ks], sA0);
      sB0 = mfma32(k0, qfB[ks], sB0);
    }
    // ================= QK half2: s-rows 32..63 =================
    f32x16 sA1 = {}, sB1 = {};
#pragma unroll
    for (int ks = 0; ks < 4; ++ks) {
      short8 k1 = *(const short8*)(kr + rb1 + ((ks * 32 + hl16) ^ sw));
      sA1 = mfma32(k1, qfA[ks], sA1);
      sB1 = mfma32(k1, qfB[ks], sB1);
    }

    // ===== softmax half1 (VALU; overlaps QK half2's MFMA issue) =====
    unsigned cA0[8], cB0[8];
#pragma unroll
    for (int i = 0; i < 8; ++i)
      cA0[i] = cvtpk(__builtin_exp2f(sA0[2 * i]), __builtin_exp2f(sA0[2 * i + 1]));
#pragma unroll
    for (int i = 0; i < 8; ++i)
      cB0[i] = cvtpk(__builtin_exp2f(sB0[2 * i]), __builtin_exp2f(sB0[2 * i + 1]));
    {
      u32x2 r;
      r = __builtin_amdgcn_permlane32_swap(cA0[0], cA0[2], false, false); cA0[0] = r[0]; cA0[2] = r[1];
      r = __builtin_amdgcn_permlane32_swap(cA0[1], cA0[3], false, false); cA0[1] = r[0]; cA0[3] = r[1];
      r = __builtin_amdgcn_permlane32_swap(cA0[4], cA0[6], false, false); cA0[4] = r[0]; cA0[6] = r[1];
      r = __builtin_amdgcn_permlane32_swap(cA0[5], cA0[7], false, false); cA0[5] = r[0]; cA0[7] = r[1];
      r = __builtin_amdgcn_permlane32_swap(cB0[0], cB0[2], false, false); cB0[0] = r[0]; cB0[2] = r[1];
      r = __builtin_amdgcn_permlane32_swap(cB0[1], cB0[3], false, false); cB0[1] = r[0]; cB0[3] = r[1];
      r = __builtin_amdgcn_permlane32_swap(cB0[4], cB0[6], false, false); cB0[4] = r[0]; cB0[6] = r[1];
      r = __builtin_amdgcn_permlane32_swap(cB0[5], cB0[7], false, false); cB0[5] = r[0]; cB0[7] = r[1];
    }
    short8 pfA0, pfA1, pfB0, pfB1;
    {
      union { unsigned u[4]; short8 s; } t2;
      t2.u[0] = cA0[0]; t2.u[1] = cA0[1]; t2.u[2] = cA0[2]; t2.u[3] = cA0[3]; pfA0 = t2.s;
      t2.u[0] = cA0[4]; t2.u[1] = cA0[5]; t2.u[2] = cA0[6]; t2.u[3] = cA0[7]; pfA1 = t2.s;
      t2.u[0] = cB0[0]; t2.u[1] = cB0[1]; t2.u[2] = cB0[2]; t2.u[3] = cB0[3]; pfB0 = t2.s;
      t2.u[0] = cB0[4]; t2.u[1] = cB0[5]; t2.u[2] = cB0[6]; t2.u[3] = cB0[7]; pfB1 = t2.s;
    }

    // ================= PV half1 (ks 0,1) =================
#pragma unroll
    for (int ks = 0; ks < 2; ++ks) {
      short8 pf = ks ? pfA1 : pfA0;
      short8 pg = ks ? pfB1 : pfB0;
      short8 v0 = *(const short8*)(vr + rb0 + ((ks * 32 + hl16) ^ sw));
      short8 v1 = *(const short8*)(vr + rb1 + ((ks * 32 + hl16) ^ sw));
      oA0 = mfma32(v0, pf, oA0);
      oA1 = mfma32(v1, pf, oA1);
      oB0 = mfma32(v0, pg, oB0);
      oB1 = mfma32(v1, pg, oB1);
      lA = mfma32(ones, pf, lA);
      lB = mfma32(ones, pg, lB);
    }

    // ===== softmax half2 (VALU; overlaps PV half1's MFMA issue) =====
    unsigned cA1[8], cB1[8];
#pragma unroll
    for (int i = 0; i < 8; ++i)
      cA1[i] = cvtpk(__builtin_exp2f(sA1[2 * i]), __builtin_exp2f(sA1[2 * i + 1]));
#pragma unroll
    for (int i = 0; i < 8; ++i)
      cB1[i] = cvtpk(__builtin_exp2f(sB1[2 * i]), __builtin_exp2f(sB1[2 * i + 1]));
    {
      u32x2 r;
      r = __builtin_amdgcn_permlane32_swap(cA1[0], cA1[2], false, false); cA1[0] = r[0]; cA1[2] = r[1];
      r = __builtin_amdgcn_permlane32_swap(cA1[1], cA1[3], false, false); cA1[1] = r[0]; cA1[3] = r[1];
      r = __builtin_amdgcn_permlane32_swap(cA1[4], cA1[6], false, false); cA1[4] = r[0]; cA1[6] = r[1];
      r = __builtin_amdgcn_permlane32_swap(cA1[5], cA1[7], false, false); cA1[5] = r[0]; cA1[7] = r[1];
      r = __builtin_amdgcn_permlane32_swap(cB1[0], cB1[2], false, false); cB1[0] = r[0]; cB1[2] = r[1];
      r = __builtin_amdgcn_permlane32_swap(cB1[1], cB1[3], false, false); cB1[1] = r[0]; cB1[3] = r[1];
      r = __builtin_amdgcn_permlane32_swap(cB1[4], cB1[6], false, false); cB1[4] = r[0]; cB1[6] = r[1];
      r = __builtin_amdgcn_permlane32_swap(cB1[5], cB1[7], false, false); cB1[5] = r[0]; cB1[7] = r[1];
    }
    short8 pfA2, pfA3, pfB2, pfB3;
    {
      union { unsigned u[4]; short8 s; } t2;
      t2.u[0] = cA1[0]; t2.u[1] = cA1[1]; t2.u[2] = cA1[2]; t2.u[3] = cA1[3]; pfA2 = t2.s;
      t2.u[0] = cA1[4]; t2.u[1] = cA1[5]; t2.u[2] = cA1[6]; t2.u[3] = cA1[7]; pfA3 = t2.s;
      t2.u[0] = cB1[0]; t2.u[1] = cB1[1]; t2.u[2] = cB1[2]; t2.u[3] = cB1[3]; pfB2 = t2.s;
      t2.u[0] = cB1[4]; t2.u[1] = cB1[5]; t2.u[2] = cB1[6]; t2.u[3] = cB1[7]; pfB3 = t2.s;
    }

    // ================= PV half2 (ks 2,3) =================
#pragma unroll
    for (int ks = 2; ks < 4; ++ks) {
      short8 pf = (ks == 2) ? pfA2 : pfA3;
      short8 pg = (ks == 2) ? pfB2 : pfB3;
      short8 v0 = *(const short8*)(vr + rb0 + ((ks * 32 + hl16) ^ sw));
      short8 v1 = *(const short8*)(vr + rb1 + ((ks * 32 + hl16) ^ sw));
      oA0 = mfma32(v0, pf, oA0);
      oA1 = mfma32(v1, pf, oA1);
      oB0 = mfma32(v0, pg, oB0);
      oB1 = mfma32(v1, pg, oB1);
      lA = mfma32(ones, pf, lA);
      lB = mfma32(ones, pg, lB);
    }

    __syncthreads();
    cur ^= 1;
  }

  // ---- combine s-halves (trivial: o and l just add) ----
  float* myc = cb + (size_t)(qh * 64 + lane) * 68;
  if (sh == 1) {
    float4* c4 = (float4*)myc;
#pragma unroll
    for (int i = 0; i < 4; ++i) {
      c4[i]      = make_float4(oA0[4*i], oA0[4*i+1], oA0[4*i+2], oA0[4*i+3]);
      c4[4 + i]  = make_float4(oA1[4*i], oA1[4*i+1], oA1[4*i+2], oA1[4*i+3]);
      c4[8 + i]  = make_float4(oB0[4*i], oB0[4*i+1], oB0[4*i+2], oB0[4*i+3]);
      c4[12 + i] = make_float4(oB1[4*i], oB1[4*i+1], oB1[4*i+2], oB1[4*i+3]);
    }
    myc[64] = lA[0]; myc[65] = lB[0];
  }
  __syncthreads();
  if (sh == 0) {
#pragma unroll
    for (int i = 0; i < 16; ++i) {
      oA0[i] += myc[i];      oA1[i] += myc[16 + i];
      oB0[i] += myc[32 + i]; oB1[i] += myc[48 + i];
    }
    float invA = 1.f / (lA[0] + myc[64]);
    float invB = 1.f / (lB[0] + myc[65]);

#pragma unroll
    for (int dblk = 0; dblk < 2; ++dblk) {
      const f32x16& a = dblk ? oA1 : oA0;
      const f32x16& bb = dblk ? oB1 : oB0;
#pragma unroll
      for (int rg = 0; rg < 4; ++rg) {
        int d0 = dblk * 32 + rg * 8 + hl * 4;
        uint2 w;
        w.x = cvtpk(a[rg * 4 + 0] * invA, a[rg * 4 + 1] * invA);
        w.y = cvtpk(a[rg * 4 + 2] * invA, a[rg * 4 + 3] * invA);
        *(uint2*)(Og + ((size_t)b * 2048 + q0) * 512 + h * 64 + d0) = w;
        w.x = cvtpk(bb[rg * 4 + 0] * invB, bb[rg * 4 + 1] * invB);
        w.y = cvtpk(bb[rg * 4 + 2] * invB, bb[rg * 4 + 3] * invB);
        *(uint2*)(Og + ((size_t)b * 2048 + q0 + 32) * 512 + h * 64 + d0) = w;
      }
    }
  }
}

// ---------------------------------------------------------------------------
extern "C" void kernel_launch(void* const* d_in, const int* in_sizes, int n_in,
                              void* d_out, int out_size, void* d_ws, size_t ws_size,
                              hipStream_t stream) {
  (void)in_sizes; (void)n_in; (void)out_size; (void)ws_size;
  const float* query = (const float*)d_in[0];
  const float* key   = (const float*)d_in[1];
  const float* value = (const float*)d_in[2];
  const float* Wq    = (const float*)d_in[3];
  const float* Wk    = (const float*)d_in[4];
  const float* Wv    = (const float*)d_in[5];
  const float* Wo    = (const float*)d_in[6];

  const size_t TOK = (size_t)NB * NL * MODEL;
  unsigned short* Qw = (unsigned short*)d_ws;
  unsigned short* Kw = Qw + TOK;
  unsigned short* Vw = Kw + TOK;   // transposed [b][h*64+d][s]
  unsigned short* Aw = Vw + TOK;   // attended [b][l][512]

  qkv512<<<768, 256, 0, stream>>>(query, key, value, Wq, Wk, Wv, Qw, Kw, Vw);
  attn64<<<512, 256, 0, stream>>>(Qw, Kw, Vw, Aw);
  gemmWo<<<256, 512, 0, stream>>>(Aw, Wo, (float*)d_out);
}